// Round 2
// baseline (20165.392 us; speedup 1.0000x reference)
//
#include <hip/hip_runtime.h>
#include <math.h>

// L=1024, B=24, D=512.  i-axis chunked by 128 to fit d_ws (~78 MiB used):
//   tk   (full)  : tanh(v . Wp_^T)            [24576 x 512]
//   tq_c (chunk) : tanh(v_chunk . Wp^T)       [3072 x 512]
//   C_c  (chunk) : attention context          [3072 x 512]
//   Gi_c (chunk) : C_c . w_ih^T + b_ih        [3072 x 1536]
//   hbuf         : GRU hidden state           [24 x 512]
// GRU: 1024 per-step launches; 96 blocks = 32 d-slices x 3 b-groups; each block
// owns 48 w_hh rows (3 gates x 16 d) and is self-sufficient for its h_new slice.

// ---------------------------------------------------------------------------
// GEMM: out[m][n] = post(A[m][:] . B[n][:] (+ bias[n])), A: MxK rm, B: NxK rm.
__launch_bounds__(256, 2)
__global__ void gemm_abt_kernel(const float* __restrict__ A, const float* __restrict__ B,
                                float* __restrict__ out, int K, int N,
                                const float* __restrict__ bias, int do_tanh) {
  __shared__ __align__(16) float As[16][136];
  __shared__ __align__(16) float Bs[16][136];
  const int m0 = blockIdx.y * 128, n0 = blockIdx.x * 128;
  const int tid = threadIdx.x;
  const int tm = (tid & 15) * 8, tn = (tid >> 4) * 8;
  const int srow = tid & 127, scol = (tid >> 7) * 8;
  const float* Ap = A + (size_t)(m0 + srow) * K + scol;
  const float* Bp = B + (size_t)(n0 + srow) * K + scol;
  float acc[8][8] = {{0.f}};
  for (int k0 = 0; k0 < K; k0 += 16) {
    const float4 a0 = *(const float4*)(Ap + k0);
    const float4 a1 = *(const float4*)(Ap + k0 + 4);
    const float4 b0 = *(const float4*)(Bp + k0);
    const float4 b1 = *(const float4*)(Bp + k0 + 4);
    __syncthreads();
    As[scol + 0][srow] = a0.x; As[scol + 1][srow] = a0.y;
    As[scol + 2][srow] = a0.z; As[scol + 3][srow] = a0.w;
    As[scol + 4][srow] = a1.x; As[scol + 5][srow] = a1.y;
    As[scol + 6][srow] = a1.z; As[scol + 7][srow] = a1.w;
    Bs[scol + 0][srow] = b0.x; Bs[scol + 1][srow] = b0.y;
    Bs[scol + 2][srow] = b0.z; Bs[scol + 3][srow] = b0.w;
    Bs[scol + 4][srow] = b1.x; Bs[scol + 5][srow] = b1.y;
    Bs[scol + 6][srow] = b1.z; Bs[scol + 7][srow] = b1.w;
    __syncthreads();
#pragma unroll
    for (int kk = 0; kk < 16; ++kk) {
      const float4 av0 = *(const float4*)&As[kk][tm];
      const float4 av1 = *(const float4*)&As[kk][tm + 4];
      const float4 bv0 = *(const float4*)&Bs[kk][tn];
      const float4 bv1 = *(const float4*)&Bs[kk][tn + 4];
      const float ar[8] = {av0.x, av0.y, av0.z, av0.w, av1.x, av1.y, av1.z, av1.w};
      const float br[8] = {bv0.x, bv0.y, bv0.z, bv0.w, bv1.x, bv1.y, bv1.z, bv1.w};
#pragma unroll
      for (int r = 0; r < 8; ++r)
#pragma unroll
        for (int c = 0; c < 8; ++c)
          acc[r][c] = fmaf(ar[r], br[c], acc[r][c]);
    }
  }
#pragma unroll
  for (int r = 0; r < 8; ++r) {
    float* o = out + (size_t)(m0 + tm + r) * N + n0 + tn;
#pragma unroll
    for (int c = 0; c < 8; ++c) {
      float val = acc[r][c];
      if (bias) val += bias[n0 + tn + c];
      if (do_tanh) val = tanhf(val);
      o[c] = val;
    }
  }
}

// ---------------------------------------------------------------------------
// Fused scores + softmax + context for one i-chunk.
// Block = (i-tile of 4, b). 256 threads (4 waves).
// Phase A: wave w does rows l = w,w+4,... scores -> sm[4][1024]
// Phase B: wave w softmaxes row w in place.
// Phase C: wave w accumulates context over l in [256w,256w+256), LDS-reduce.
__launch_bounds__(256, 3)
__global__ void attn_kernel(const float* __restrict__ tq, const float* __restrict__ tk,
                            const float* __restrict__ Vv, const float* __restrict__ v,
                            float* __restrict__ Cout) {
  const int b = blockIdx.y;
  const int it = blockIdx.x;           // i-tile within chunk (il = it*4+ii)
  const int tid = threadIdx.x;
  const int wave = tid >> 6, lane = tid & 63;
  const int h8 = lane * 8;
  __shared__ __align__(16) float sm[4][1024];
  __shared__ __align__(16) float red[4][4][512];

  float q[4][8];
#pragma unroll
  for (int ii = 0; ii < 4; ++ii) {
    const float* qp = tq + ((size_t)(it * 4 + ii) * 24 + b) * 512 + h8;
    const float4 q0 = *(const float4*)qp;
    const float4 q1 = *(const float4*)(qp + 4);
    q[ii][0] = q0.x; q[ii][1] = q0.y; q[ii][2] = q0.z; q[ii][3] = q0.w;
    q[ii][4] = q1.x; q[ii][5] = q1.y; q[ii][6] = q1.z; q[ii][7] = q1.w;
  }
  const float* vp = Vv + (size_t)b * 512 + h8;
  const float4 v0 = *(const float4*)vp;
  const float4 v1 = *(const float4*)(vp + 4);
  const float vv[8] = {v0.x, v0.y, v0.z, v0.w, v1.x, v1.y, v1.z, v1.w};

  for (int l = wave; l < 1024; l += 4) {
    const float* kp = tk + ((size_t)l * 24 + b) * 512 + h8;
    const float4 k0 = *(const float4*)kp;
    const float4 k1 = *(const float4*)(kp + 4);
    const float kkv[8] = {k0.x, k0.y, k0.z, k0.w, k1.x, k1.y, k1.z, k1.w};
    float acc0 = 0.f, acc1 = 0.f, acc2 = 0.f, acc3 = 0.f;
#pragma unroll
    for (int j = 0; j < 8; ++j) {
      const float bk = kkv[j];
      const float vj = vv[j];
      // tanh(q+k) = (tq+tk)/(1+tq*tk)
      { const float a = q[0][j];
        acc0 = fmaf(vj * (a + bk), __builtin_amdgcn_rcpf(fmaf(a, bk, 1.0f)), acc0); }
      { const float a = q[1][j];
        acc1 = fmaf(vj * (a + bk), __builtin_amdgcn_rcpf(fmaf(a, bk, 1.0f)), acc1); }
      { const float a = q[2][j];
        acc2 = fmaf(vj * (a + bk), __builtin_amdgcn_rcpf(fmaf(a, bk, 1.0f)), acc2); }
      { const float a = q[3][j];
        acc3 = fmaf(vj * (a + bk), __builtin_amdgcn_rcpf(fmaf(a, bk, 1.0f)), acc3); }
    }
#pragma unroll
    for (int mask = 32; mask; mask >>= 1) {
      acc0 += __shfl_xor(acc0, mask, 64);
      acc1 += __shfl_xor(acc1, mask, 64);
      acc2 += __shfl_xor(acc2, mask, 64);
      acc3 += __shfl_xor(acc3, mask, 64);
    }
    if (lane == 0) {
      sm[0][l] = acc0; sm[1][l] = acc1; sm[2][l] = acc2; sm[3][l] = acc3;
    }
  }
  __syncthreads();

  // softmax of row `wave`, in place
  {
    float* row = sm[wave];
    float m = -1e30f;
    for (int t = lane; t < 1024; t += 64) m = fmaxf(m, row[t]);
#pragma unroll
    for (int mask = 32; mask; mask >>= 1) m = fmaxf(m, __shfl_xor(m, mask, 64));
    float s = 0.f;
    float e0 = __expf(row[lane] - m);
    float e1 = __expf(row[lane + 64] - m);
    // strided loop (16 elems/lane)
    s = 0.f;
    for (int t = lane; t < 1024; t += 64) {
      const float e = __expf(row[t] - m);
      row[t] = e;
      s += e;
    }
    (void)e0; (void)e1;
#pragma unroll
    for (int mask = 32; mask; mask >>= 1) s += __shfl_xor(s, mask, 64);
    const float inv = 1.0f / s;
    for (int t = lane; t < 1024; t += 64) row[t] *= inv;
  }
  __syncthreads();

  // Phase C: context. wave w covers l in [256w, 256w+256), lane owns d-slice h8.
  float ca[4][8] = {{0.f}};
  const int l0 = wave * 256;
  for (int l = l0; l < l0 + 256; ++l) {
    const float* vrow = v + ((size_t)l * 24 + b) * 512 + h8;
    const float4 x0 = *(const float4*)vrow;
    const float4 x1 = *(const float4*)(vrow + 4);
    const float a0 = sm[0][l], a1 = sm[1][l], a2 = sm[2][l], a3 = sm[3][l];
    const float xv[8] = {x0.x, x0.y, x0.z, x0.w, x1.x, x1.y, x1.z, x1.w};
#pragma unroll
    for (int j = 0; j < 8; ++j) {
      ca[0][j] = fmaf(a0, xv[j], ca[0][j]);
      ca[1][j] = fmaf(a1, xv[j], ca[1][j]);
      ca[2][j] = fmaf(a2, xv[j], ca[2][j]);
      ca[3][j] = fmaf(a3, xv[j], ca[3][j]);
    }
  }
#pragma unroll
  for (int ii = 0; ii < 4; ++ii) {
    *(float4*)&red[wave][ii][h8]     = make_float4(ca[ii][0], ca[ii][1], ca[ii][2], ca[ii][3]);
    *(float4*)&red[wave][ii][h8 + 4] = make_float4(ca[ii][4], ca[ii][5], ca[ii][6], ca[ii][7]);
  }
  __syncthreads();
  // final reduce: thread t -> (ii = t>>6, d0 = (t&63)*8)
  {
    const int ii = tid >> 6;
    const int d0 = (tid & 63) * 8;
    float4 s0 = *(const float4*)&red[0][ii][d0];
    float4 s1 = *(const float4*)&red[0][ii][d0 + 4];
#pragma unroll
    for (int w = 1; w < 4; ++w) {
      const float4 r0 = *(const float4*)&red[w][ii][d0];
      const float4 r1 = *(const float4*)&red[w][ii][d0 + 4];
      s0.x += r0.x; s0.y += r0.y; s0.z += r0.z; s0.w += r0.w;
      s1.x += r1.x; s1.y += r1.y; s1.z += r1.z; s1.w += r1.w;
    }
    float* o = Cout + ((size_t)(it * 4 + ii) * 24 + b) * 512 + d0;
    *(float4*)o = s0;
    *(float4*)(o + 4) = s1;
  }
}

// ---------------------------------------------------------------------------
// One GRU time step. Grid 96 = 32 d-slices (js) x 3 b-groups (pg).
// Block owns d in [js*16, js*16+16), gates {r,z,n} (48 w_hh rows), b-group of 8.
// 192 threads: t -> row r = t%48, b_loc = t/48 (and b_loc+4). Self-sufficient
// h_new for its slice; h exchanged via global hbuf between launches.
__launch_bounds__(192)
__global__ void gru_step_kernel(const float* __restrict__ gi_step,   // [24][1536]
                                const float* __restrict__ w_hh,      // [1536][512]
                                const float* __restrict__ b_hh,      // [1536]
                                const float* __restrict__ h_prev,    // [24][512]
                                float* __restrict__ hbuf,            // [24][512]
                                float* __restrict__ out_step) {      // [24][512]
  const int js = blockIdx.x & 31;        // d-slice
  const int pg = blockIdx.x >> 5;        // b-group (0..2)
  const int t = threadIdx.x;
  __shared__ __align__(16) float h_lds[8][516];
  __shared__ float gh_lds[8][48];

  // load h for the 8 batches of this group
  for (int idx = t; idx < 1024; idx += 192) {   // 1024 float4 = 8*512 floats
    const int bb = idx >> 7;
    const int kk = (idx & 127) * 4;
    *(float4*)&h_lds[bb][kk] = *(const float4*)(h_prev + (size_t)(pg * 8 + bb) * 512 + kk);
  }
  __syncthreads();

  // Phase W: 2 dots per thread (same w row, batches b_loc and b_loc+4)
  {
    const int b_loc = t / 48;
    const int r = t - b_loc * 48;
    const int jg = (r >> 4) * 512 + js * 16 + (r & 15);
    const float* wrow = w_hh + (size_t)jg * 512;
    float acc1 = 0.f, acc2 = 0.f;
#pragma unroll 4
    for (int k = 0; k < 512; k += 4) {
      const float4 wv = *(const float4*)(wrow + k);
      const float4 h1 = *(const float4*)&h_lds[b_loc][k];
      const float4 h2 = *(const float4*)&h_lds[b_loc + 4][k];
      acc1 = fmaf(wv.x, h1.x, fmaf(wv.y, h1.y, fmaf(wv.z, h1.z, fmaf(wv.w, h1.w, acc1))));
      acc2 = fmaf(wv.x, h2.x, fmaf(wv.y, h2.y, fmaf(wv.z, h2.z, fmaf(wv.w, h2.w, acc2))));
    }
    const float bias = b_hh[jg];
    gh_lds[b_loc][r] = acc1 + bias;
    gh_lds[b_loc + 4][r] = acc2 + bias;
  }
  __syncthreads();

  // Phase H: 128 outputs (8 b x 16 d)
  if (t < 128) {
    const int b_loc = t >> 4;
    const int dd = t & 15;
    const int d_g = js * 16 + dd;
    const int b_g = pg * 8 + b_loc;
    const float ghr = gh_lds[b_loc][dd];
    const float ghz = gh_lds[b_loc][16 + dd];
    const float ghn = gh_lds[b_loc][32 + dd];
    const float* gi = gi_step + (size_t)b_g * 1536;
    const float gir = gi[d_g];
    const float giz = gi[512 + d_g];
    const float gin = gi[1024 + d_g];
    const float h_old = h_lds[b_loc][d_g];
    const float r = 1.0f / (1.0f + __expf(-(gir + ghr)));
    const float z = 1.0f / (1.0f + __expf(-(giz + ghz)));
    const float n = tanhf(gin + r * ghn);
    const float hn = (1.0f - z) * n + z * h_old;
    hbuf[(size_t)b_g * 512 + d_g] = hn;
    out_step[(size_t)b_g * 512 + d_g] = hn;
  }
}

// ---------------------------------------------------------------------------
extern "C" void kernel_launch(void* const* d_in, const int* in_sizes, int n_in,
                              void* d_out, int out_size, void* d_ws, size_t ws_size,
                              hipStream_t stream) {
  (void)in_sizes; (void)n_in; (void)out_size; (void)ws_size;
  const float* v    = (const float*)d_in[0];
  const float* h0   = (const float*)d_in[1];
  const float* Vv   = (const float*)d_in[2];
  const float* Wp   = (const float*)d_in[3];
  const float* Wp_  = (const float*)d_in[4];
  const float* w_ih = (const float*)d_in[5];
  const float* w_hh = (const float*)d_in[6];
  const float* b_ih = (const float*)d_in[7];
  const float* b_hh = (const float*)d_in[8];
  float* out = (float*)d_out;

  // workspace layout (floats); total 20,459,520 fl = 78.05 MiB
  float* ws   = (float*)d_ws;
  float* tk   = ws;                                  // 12,582,912
  float* tq_c = tk + (size_t)12582912;               //  1,572,864
  float* C_c  = tq_c + (size_t)1572864;              //  1,572,864
  float* Gi_c = C_c + (size_t)1572864;               //  4,718,592
  float* hbuf = Gi_c + (size_t)4718592;              //     12,288

  // full key projection: tk = tanh(v . Wp_^T)
  gemm_abt_kernel<<<dim3(4, 192), 256, 0, stream>>>(v, Wp_, tk, 512, 512, nullptr, 1);

  for (int c = 0; c < 8; ++c) {
    const float* v_chunk = v + (size_t)c * 128 * 24 * 512;
    // query projection for this chunk
    gemm_abt_kernel<<<dim3(4, 24), 256, 0, stream>>>(v_chunk, Wp, tq_c, 512, 512, nullptr, 1);
    // fused scores + softmax + context
    attn_kernel<<<dim3(32, 24), 256, 0, stream>>>(tq_c, tk, Vv, v, C_c);
    // Gi = C . w_ih^T + b_ih
    gemm_abt_kernel<<<dim3(12, 24), 256, 0, stream>>>(C_c, w_ih, Gi_c, 512, 1536, b_ih, 0);
    // 128 sequential GRU steps
    for (int il = 0; il < 128; ++il) {
      const int step = c * 128 + il;
      const float* h_prev = (step == 0) ? h0 : hbuf;
      gru_step_kernel<<<96, 192, 0, stream>>>(Gi_c + (size_t)il * 24 * 1536,
                                              w_hh, b_hh, h_prev, hbuf,
                                              out + (size_t)step * 24 * 512);
    }
  }
}